// Round 10
// baseline (271.219 us; speedup 1.0000x reference)
//
#include <hip/hip_runtime.h>

// ---------------------------------------------------------------------------
// MHA without softmax, fully reassociated:
//   out[b] = query[b] @ F[b] + cv[b]
//   F[b]   = 0.125 * WqM[b] @ Wo,  WqM[b] = Wq . blockdiag_h(M[b,h])
//   M[b,h] = Wk_h^T C[b] Wv_h + (Wk_h^T ksum) bv_h^T + bk_h (vsum^T Wv_h) + S bk_h bv_h^T
//   C[b]   = key[b]^T value[b]   (D := value^T key = C^T)
// Round 10: GEMM core untouched (937 TF-eq ceiling). Overlap pass:
//  - Q-image build moved INTO the under-filled mstep (256-blk) and wqm
//    (512-blk) launches as extra blocks -> off the critical path.
//  - reduceks/uvpart/reduceuv -> single uvdirect kernel.
//  - cvpart fused into FT-gemm launch; cvred+FTimg one launch.
//  15 -> 11 launches. Layout: Qimg [64,96MiB), FTimg [0,16MiB); peak
//  unchanged (100.9 MB, proven available by rounds 7-9).
// ---------------------------------------------------------------------------

typedef __attribute__((ext_vector_type(8))) short short8;
typedef __attribute__((ext_vector_type(8))) unsigned short ushort8;
typedef __attribute__((ext_vector_type(4))) float f32x4;

__device__ __forceinline__ unsigned short f2bf(float x) {
  unsigned u = __builtin_bit_cast(unsigned, x);
  u += 0x7fffu + ((u >> 16) & 1u);  // RNE
  return (unsigned short)(u >> 16);
}
__device__ __forceinline__ float bf2f(unsigned short b) {
  unsigned u = ((unsigned)b) << 16;
  return __builtin_bit_cast(float, u);
}

__device__ __forceinline__ void gload16(const unsigned short* g, unsigned short* l) {
  __builtin_amdgcn_global_load_lds(
      (const __attribute__((address_space(1))) unsigned int*)g,
      (__attribute__((address_space(3))) unsigned int*)l, 16, 0, 0);
}

// ---------------------------------------------------------------------------
// build_img: stage one 128x32 tile of logical R[rows][K] into LDS (fp32),
// then write the split-bf16 blob: 8192 ushorts = hi[4][128][8] || lo[4][128][8]
// ---------------------------------------------------------------------------
__device__ __forceinline__ void build_img(const float* __restrict__ s,
                                          int transposed, int nsum,
                                          long long sumStride, int rb, int kt,
                                          float (*tile)[36],
                                          unsigned short* __restrict__ blob) {
  const int t = threadIdx.x;
  if (!transposed) {
#pragma unroll
    for (int p = 0; p < 4; ++p) {
      const int idx = p * 1024 + t * 4;
      const int r = idx >> 5, k = idx & 31;
      const size_t off = (size_t)(rb * 128 + r) * 1024 + kt * 32 + k;
      float4 v = *(const float4*)&s[off];
      if (nsum == 2) {
        float4 u = *(const float4*)&s[off + sumStride];
        v.x += u.x; v.y += u.y; v.z += u.z; v.w += u.w;
      }
      *(float4*)&tile[r][k] = v;
    }
  } else {
#pragma unroll
    for (int p = 0; p < 4; ++p) {
      const int idx = p * 1024 + t * 4;
      const int k = idx >> 7, r = idx & 127;
      const size_t off = (size_t)(kt * 32 + k) * 1024 + rb * 128 + r;
      float4 v = *(const float4*)&s[off];
      tile[r + 0][k] = v.x;
      tile[r + 1][k] = v.y;
      tile[r + 2][k] = v.z;
      tile[r + 3][k] = v.w;
    }
  }
  __syncthreads();
  const int r = t >> 1, kh = (t & 1) * 16;
  ushort8 hi0, lo0, hi1, lo1;
#pragma unroll
  for (int j = 0; j < 8; ++j) {
    float x = tile[r][kh + j];
    unsigned short h = f2bf(x);
    hi0[j] = h;
    lo0[j] = f2bf(x - bf2f(h));
    float y = tile[r][kh + 8 + j];
    unsigned short g = f2bf(y);
    hi1[j] = g;
    lo1[j] = f2bf(y - bf2f(g));
  }
  const int k0sl = kh >> 3;  // 0 or 2
  *(ushort8*)&blob[k0sl * 1024 + r * 8] = hi0;
  *(ushort8*)&blob[(k0sl + 1) * 1024 + r * 8] = hi1;
  *(ushort8*)&blob[4096 + k0sl * 1024 + r * 8] = lo0;
  *(ushort8*)&blob[4096 + (k0sl + 1) * 1024 + r * 8] = lo1;
}

// ---------------------------------------------------------------------------
// gemm_core: C[m][n] (+bias[n]) = sum_k A[m][k]*BT[n][k], split-bf16 3-MFMA.
// 128x128 tile, BK=32, 4 waves; LDS double-buffer via global_load_lds.
// (proven round-3..9 loop, verbatim; decode hoisted to callers)
// ---------------------------------------------------------------------------
__device__ __forceinline__ void gemm_core(
    unsigned short (*sAB)[16384], int bx, int by, int bz0,
    const unsigned short* __restrict__ Aimg, long long sAb,
    const unsigned short* __restrict__ Bimg, long long sBb,
    const float* __restrict__ bias, long long sBiasB, float* __restrict__ C,
    long long sCb, int NKT, int nsplit, long long sSplit) {
  const int tid = threadIdx.x, w = tid >> 6, l = tid & 63;
  const int batch = bz0 / nsplit, split = bz0 - batch * nsplit;
  const int NKT0 = NKT / nsplit, kt0 = split * NKT0;

  const unsigned short* Ab = Aimg + (size_t)batch * sAb + (size_t)bx * NKT * 8192;
  const unsigned short* Bb = Bimg + (size_t)batch * sBb + (size_t)by * NKT * 8192;

  f32x4 acc[4][4];
#pragma unroll
  for (int m = 0; m < 4; ++m)
#pragma unroll
    for (int n = 0; n < 4; ++n) acc[m][n] = f32x4{0.f, 0.f, 0.f, 0.f};

  const int wr = (w >> 1) * 64, wc = (w & 1) * 64, lr = l & 15, ksl = l >> 4;
  const int stg = w * 512 + l * 8;

#define STAGE(KT, BUF)                                                        \
  {                                                                           \
    const unsigned short* As_ = Ab + (size_t)(KT)*8192;                       \
    const unsigned short* Bs_ = Bb + (size_t)(KT)*8192;                       \
    _Pragma("unroll") for (int i = 0; i < 4; ++i)                             \
        gload16(As_ + i * 2048 + stg, &sAB[BUF][i * 2048 + w * 512]);         \
    _Pragma("unroll") for (int i = 0; i < 4; ++i)                             \
        gload16(Bs_ + i * 2048 + stg, &sAB[BUF][8192 + i * 2048 + w * 512]);  \
  }

  STAGE(kt0, 0);
  for (int kk = 0; kk < NKT0; ++kk) {
    __syncthreads();  // drains vmcnt(0): buf kk&1 ready; prev reads done
    if (kk + 1 < NKT0) STAGE(kt0 + kk + 1, (kk + 1) & 1);
    const unsigned short* sb = sAB[kk & 1];
    short8 ah[4], al[4], bh[4], bl[4];
#pragma unroll
    for (int m = 0; m < 4; ++m) {
      const int ro = ksl * 1024 + (wr + m * 16 + lr) * 8;
      ah[m] = *(const short8*)&sb[ro];
      al[m] = *(const short8*)&sb[4096 + ro];
    }
#pragma unroll
    for (int n = 0; n < 4; ++n) {
      const int ro = ksl * 1024 + (wc + n * 16 + lr) * 8;
      bh[n] = *(const short8*)&sb[8192 + ro];
      bl[n] = *(const short8*)&sb[12288 + ro];
    }
#pragma unroll
    for (int m = 0; m < 4; ++m)
#pragma unroll
      for (int n = 0; n < 4; ++n) {
        acc[m][n] = __builtin_amdgcn_mfma_f32_16x16x32_bf16(ah[m], bh[n], acc[m][n], 0, 0, 0);
        acc[m][n] = __builtin_amdgcn_mfma_f32_16x16x32_bf16(ah[m], bl[n], acc[m][n], 0, 0, 0);
        acc[m][n] = __builtin_amdgcn_mfma_f32_16x16x32_bf16(al[m], bh[n], acc[m][n], 0, 0, 0);
      }
  }
#undef STAGE

  float* Cb = C + (size_t)split * sSplit + (size_t)batch * sCb;
  const size_t m0 = (size_t)bx * 128, n0 = (size_t)by * 128;
#pragma unroll
  for (int n = 0; n < 4; ++n) {
    const size_t col = n0 + wc + n * 16 + lr;
    const float bval = bias ? bias[(size_t)batch * sBiasB + col] : 0.0f;
#pragma unroll
    for (int m = 0; m < 4; ++m) {
      const size_t rb = m0 + wr + m * 16 + ksl * 4;
#pragma unroll
      for (int r = 0; r < 4; ++r)
        Cb[(rb + r) * 1024 + col] = acc[m][n][r] + bval;
    }
  }
}

// generic 3D-grid gemm (D, T, final)
__global__ __launch_bounds__(256) void gemm_img(
    const unsigned short* __restrict__ Aimg, long long sAb,
    const unsigned short* __restrict__ Bimg, long long sBb,
    const float* __restrict__ bias, long long sBiasB, float* __restrict__ C,
    long long sCb, int NKT, int nsplit, long long sSplit) {
  __shared__ __align__(16) unsigned short sAB[2][16384];
  const int gx = gridDim.x, gy = gridDim.y;
  int flat = blockIdx.x + gx * (blockIdx.y + gy * blockIdx.z);
  const int total = gx * gy * gridDim.z;
  flat = (flat & 7) * (total >> 3) + (flat >> 3);
  const int bx = flat % gx;
  const int rest = flat / gx;
  gemm_core(sAB, bx, rest % gy, rest / gy, Aimg, sAb, Bimg, sBb, bias, sBiasB,
            C, sCb, NKT, nsplit, sSplit);
}

// ---------------------------------------------------------------------------
// kvimg: images of key^T (z0-3) and value^T (z4-7) + fused column-sum
// partials. grid (8,64,8).
// ---------------------------------------------------------------------------
__global__ __launch_bounds__(256) void kvimg(const float* __restrict__ key,
                                             const float* __restrict__ value,
                                             unsigned short* __restrict__ KTimg,
                                             float* __restrict__ kvpart) {
  __shared__ __align__(16) float tile[128][36];
  const int rb = blockIdx.x, kt = blockIdx.y, z = blockIdx.z;
  const float* s = (z < 4) ? key + (size_t)z * 2097152
                           : value + (size_t)(z - 4) * 2097152;
  unsigned short* blob = KTimg + ((size_t)(z * 8 + rb) * 64 + kt) * 8192;
  build_img(s, 1, 1, 0, rb, kt, tile, blob);
  const int t = threadIdx.x, r = t >> 1, kh = (t & 1) * 16;
  float sum = 0.f;
#pragma unroll
  for (int j = 0; j < 16; ++j) sum += tile[r][kh + j];
  sum += __shfl_xor(sum, 1);
  if ((t & 1) == 0)
    kvpart[((size_t)z * 64 + kt) * 1024 + rb * 128 + r] = sum;
}

// ---------------------------------------------------------------------------
// uvdirect: uv[(kv*4+b)*1024+i] = sum_d W[d][i] * (sum_kt kvpart[z][kt][d])
// grid 32 = (iseg 4) x (kv 2) x (b 4). Replaces reduceks+uvpart+reduceuv.
// ---------------------------------------------------------------------------
__global__ __launch_bounds__(256) void uvdirect(const float* __restrict__ kvpart,
                                                const float* __restrict__ Wk,
                                                const float* __restrict__ Wv,
                                                float* __restrict__ uv) {
  __shared__ float s[1024];
  const int bid = blockIdx.x;
  const int iseg = bid & 3, kv = (bid >> 2) & 1, b = bid >> 3;
  const int t = threadIdx.x;
  const int z = kv * 4 + b;
  for (int d = t; d < 1024; d += 256) {
    float a = 0.f;
    for (int kt = 0; kt < 64; ++kt)
      a += kvpart[((size_t)(z * 64 + kt)) * 1024 + d];
    s[d] = a;
  }
  __syncthreads();
  const float* W = kv ? Wv : Wk;
  const int i = iseg * 256 + t;
  float a = 0.f;
  for (int d = 0; d < 1024; ++d) a += W[(size_t)d * 1024 + i] * s[d];
  uv[(size_t)z * 1024 + i] = a;
}

// ---------------------------------------------------------------------------
// imgA: Dimg (z0-3, nsum=dsplit) + WkT (z4) + WoT (z5). grid (8,32,6).
// ---------------------------------------------------------------------------
__global__ __launch_bounds__(256) void imgA(
    const float* __restrict__ Dpart, int dsplit, const float* __restrict__ Wk,
    const float* __restrict__ Wo, unsigned short* __restrict__ Dimg,
    unsigned short* __restrict__ WkTimg, unsigned short* __restrict__ WoTimg) {
  __shared__ __align__(16) float tile[128][36];
  const int rb = blockIdx.x, kt = blockIdx.y, z = blockIdx.z;
  if (z < 4) {
    unsigned short* blob = Dimg + ((size_t)(z * 8 + rb) * 32 + kt) * 8192;
    build_img(Dpart + (size_t)z * 1048576, 0, dsplit, 4194304, rb, kt, tile,
              blob);
  } else if (z == 4) {
    unsigned short* blob = WkTimg + ((size_t)rb * 32 + kt) * 8192;
    build_img(Wk, 1, 1, 0, rb, kt, tile, blob);
  } else {
    unsigned short* blob = WoTimg + ((size_t)rb * 32 + kt) * 8192;
    build_img(Wo, 1, 1, 0, rb, kt, tile, blob);
  }
}

// ---------------------------------------------------------------------------
// mstepq: mstep (bid<256) + Q-image batches 0,1 (bid 256..1279).
// mstep: Mpart[chunk][bh][r][c] = sum_{e in chunk} (T0+T1)[b][h64+r][e]*Wv[e][h64+c]
// ---------------------------------------------------------------------------
__global__ __launch_bounds__(256) void mstepq(const float* __restrict__ T,
                                              long long tSplit,
                                              const float* __restrict__ Wv,
                                              float* __restrict__ Mpart,
                                              const float* __restrict__ query,
                                              unsigned short* __restrict__ Qimg) {
  __shared__ __align__(16) float sh[2 * 64 * 68];
  const int bid = blockIdx.x;
  const int tid = threadIdx.x;
  if (bid >= 256) {
    const int qid = bid - 256;  // [0,1024): batches 0,1
    const int b = qid >> 9, rem = qid & 511, rb = rem & 15, kt = rem >> 4;
    build_img(query + (size_t)b * 2097152, 0, 1, 0, rb, kt,
              (float(*)[36])sh, Qimg + ((size_t)(b * 16 + rb) * 32 + kt) * 8192);
    return;
  }
  const int chunk = bid & 3, bh = bid >> 2;
  const int b = bh >> 4, h = bh & 15;
  float (*Ts)[68] = (float(*)[68])sh;
  float (*Ws)[68] = (float(*)[68])(sh + 64 * 68);
  const int r0 = tid >> 4, c0 = (tid & 15) * 4;
  float acc[4][4] = {};
  const int e0 = chunk * 256;
  for (int slab = 0; slab < 4; ++slab) {
    __syncthreads();
#pragma unroll
    for (int t = 0; t < 4; ++t) {
      const int task = tid + t * 256;
      const int si = task >> 4, c4 = (task & 15) * 4;
      const size_t toff = (size_t)b * 1048576 + (size_t)(h * 64 + si) * 1024 +
                          e0 + slab * 64 + c4;
      float4 tv = *(const float4*)&T[toff];
      float4 tu = *(const float4*)&T[toff + tSplit];
      tv.x += tu.x; tv.y += tu.y; tv.z += tu.z; tv.w += tu.w;
      *(float4*)&Ts[si][c4] = tv;
      *(float4*)&Ws[si][c4] =
          *(const float4*)&Wv[(size_t)(e0 + slab * 64 + si) * 1024 + h * 64 + c4];
    }
    __syncthreads();
    for (int e = 0; e < 64; ++e) {
      const float4 wv = *(const float4*)&Ws[e][c0];
#pragma unroll
      for (int i = 0; i < 4; ++i) {
        const float tt = Ts[r0 + 16 * i][e];
        acc[i][0] += tt * wv.x;
        acc[i][1] += tt * wv.y;
        acc[i][2] += tt * wv.z;
        acc[i][3] += tt * wv.w;
      }
    }
  }
  float* outp = Mpart + ((size_t)chunk * 64 + bh) * 4096;
#pragma unroll
  for (int i = 0; i < 4; ++i)
    *(float4*)&outp[(r0 + 16 * i) * 64 + c0] = *(float4*)&acc[i][0];
}

// M = sum(Mpart) + rank-1 bias corrections
__global__ __launch_bounds__(256) void reduce4corr(
    const float* __restrict__ Mpart, const float* __restrict__ uv,
    const float* __restrict__ bk, const float* __restrict__ bv,
    float* __restrict__ M) {
  const int idx = blockIdx.x * 256 + threadIdx.x;  // 262144
  const int bh = idx >> 12, b = bh >> 4, h = bh & 15;
  const int rc = idx & 4095;
  const int r = h * 64 + (rc >> 6), c = h * 64 + (rc & 63);
  float s = Mpart[idx] + Mpart[262144 + idx] + Mpart[524288 + idx] +
            Mpart[786432 + idx];
  s += uv[b * 1024 + r] * bv[c] + bk[r] * uv[4096 + b * 1024 + c] +
       2048.0f * bk[r] * bv[c];
  M[idx] = s;
}

// ---------------------------------------------------------------------------
// wqmq: wqm (bid<512, writes WqM split-bf16 image directly + bqM on dseg==0)
// + Q-image batches 2,3 (bid 512..1535).
// ---------------------------------------------------------------------------
__global__ __launch_bounds__(256) void wqmq(const float* __restrict__ M,
                                            const float* __restrict__ Wq,
                                            const float* __restrict__ bq,
                                            unsigned short* __restrict__ img,
                                            float* __restrict__ bqM,
                                            const float* __restrict__ query,
                                            unsigned short* __restrict__ Qimg) {
  __shared__ __align__(16) float sh[(128 + 64) * 68];
  const int bid = blockIdx.x;
  const int t = threadIdx.x;
  if (bid >= 512) {
    const int qid = 1024 + (bid - 512);  // batches 2,3
    const int b = qid >> 9, rem = qid & 511, rb = rem & 15, kt = rem >> 4;
    build_img(query + (size_t)b * 2097152, 0, 1, 0, rb, kt,
              (float(*)[36])sh, Qimg + ((size_t)(b * 16 + rb) * 32 + kt) * 8192);
    return;
  }
  const int dseg = bid & 7, h = (bid >> 3) & 15, b = bid >> 7;
  float (*WqS)[68] = (float(*)[68])sh;
  float (*Ms)[68] = (float(*)[68])(sh + 128 * 68);
#pragma unroll
  for (int it = 0; it < 8; ++it) {
    const int task = t + it * 256;
    const int row = task >> 4, c4 = (task & 15) * 4;
    *(float4*)&WqS[row][c4] =
        *(const float4*)&Wq[(size_t)(dseg * 128 + row) * 1024 + h * 64 + c4];
  }
#pragma unroll
  for (int it = 0; it < 4; ++it) {
    const int task = t + it * 256;
    const int row = task >> 4, c4 = (task & 15) * 4;
    *(float4*)&Ms[row][c4] =
        *(const float4*)&M[((size_t)(b * 16 + h)) * 4096 + row * 64 + c4];
  }
  __syncthreads();

  const int c0 = (t & 7) * 8;
  const int d0 = t >> 3;
  float4 a0[4], a1[4];
#pragma unroll
  for (int i = 0; i < 4; ++i) {
    a0[i] = float4{0.f, 0.f, 0.f, 0.f};
    a1[i] = float4{0.f, 0.f, 0.f, 0.f};
  }
  for (int r = 0; r < 64; ++r) {
    const float4 m0 = *(const float4*)&Ms[r][c0];
    const float4 m1 = *(const float4*)&Ms[r][c0 + 4];
#pragma unroll
    for (int i = 0; i < 4; ++i) {
      const float w = WqS[d0 + 32 * i][r];
      a0[i].x += w * m0.x; a0[i].y += w * m0.y; a0[i].z += w * m0.z; a0[i].w += w * m0.w;
      a1[i].x += w * m1.x; a1[i].y += w * m1.y; a1[i].z += w * m1.z; a1[i].w += w * m1.w;
    }
  }
  const int kt = h * 2 + (c0 >> 5);
  const int ksl = (c0 >> 3) & 3;
  unsigned short* blob = img + ((size_t)((b * 8 + dseg) * 32 + kt)) * 8192;
#pragma unroll
  for (int i = 0; i < 4; ++i) {
    const int r = d0 + 32 * i;
    float v[8] = {a0[i].x * 0.125f, a0[i].y * 0.125f, a0[i].z * 0.125f,
                  a0[i].w * 0.125f, a1[i].x * 0.125f, a1[i].y * 0.125f,
                  a1[i].z * 0.125f, a1[i].w * 0.125f};
    ushort8 hi, lo;
#pragma unroll
    for (int j = 0; j < 8; ++j) {
      unsigned short hh = f2bf(v[j]);
      hi[j] = hh;
      lo[j] = f2bf(v[j] - bf2f(hh));
    }
    *(ushort8*)&blob[ksl * 1024 + r * 8] = hi;
    *(ushort8*)&blob[4096 + ksl * 1024 + r * 8] = lo;
  }

  if (dseg == 0 && t < 64) {
    float s = 0.f;
#pragma unroll
    for (int r = 0; r < 64; ++r) s += bq[h * 64 + r] * Ms[r][t];
    bqM[(size_t)b * 1024 + h * 64 + t] = s;
  }
}

// ---------------------------------------------------------------------------
// ftcombo: cvpart (bid<32) + FT gemm (512 blocks, split-K x2).
// ---------------------------------------------------------------------------
__global__ __launch_bounds__(256) void ftcombo(
    const float* __restrict__ bqM, const float* __restrict__ Wo,
    float* __restrict__ cvpartb, const unsigned short* __restrict__ WoTimg,
    const unsigned short* __restrict__ WqMimg, float* __restrict__ FTpart) {
  __shared__ __align__(16) unsigned short sAB[2][16384];
  const int bid = blockIdx.x;
  if (bid < 32) {
    const int jseg = bid & 3, ks = bid >> 2;
    const int j = jseg * 256 + threadIdx.x;
    float s0 = 0.f, s1 = 0.f, s2 = 0.f, s3 = 0.f;
    for (int k = 0; k < 128; ++k) {
      const float wv = Wo[(size_t)(ks * 128 + k) * 1024 + j];
      s0 += bqM[ks * 128 + k] * wv;
      s1 += bqM[1024 + ks * 128 + k] * wv;
      s2 += bqM[2048 + ks * 128 + k] * wv;
      s3 += bqM[3072 + ks * 128 + k] * wv;
    }
    cvpartb[((size_t)0 * 8 + ks) * 1024 + j] = s0;
    cvpartb[((size_t)1 * 8 + ks) * 1024 + j] = s1;
    cvpartb[((size_t)2 * 8 + ks) * 1024 + j] = s2;
    cvpartb[((size_t)3 * 8 + ks) * 1024 + j] = s3;
    return;
  }
  const int flat0 = bid - 32;  // [0,512)
  const int flat = (flat0 & 7) * 64 + (flat0 >> 3);
  gemm_core(sAB, flat & 7, (flat >> 3) & 7, flat >> 6, WoTimg, 0, WqMimg,
            2097152, (const float*)nullptr, 0, FTpart, 1048576, 32, 2, 4194304);
}

// ---------------------------------------------------------------------------
// imgb2: cvred (bid<16) + FTimg build (1024) [+ Qimg build, small path only].
// ---------------------------------------------------------------------------
__global__ __launch_bounds__(256) void imgb2(
    const float* __restrict__ cvpartb, const float* __restrict__ bo,
    float* __restrict__ cv, const float* __restrict__ FTpart,
    unsigned short* __restrict__ FTimg, const float* __restrict__ query,
    unsigned short* __restrict__ Qimg) {
  __shared__ __align__(16) float tile[128][36];
  const int bid = blockIdx.x;
  if (bid < 16) {
    const int idx = bid * 256 + threadIdx.x;
    const int b = idx >> 10, j = idx & 1023;
    float s = 0.f;
#pragma unroll
    for (int ks = 0; ks < 8; ++ks)
      s += cvpartb[((size_t)b * 8 + ks) * 1024 + j];
    cv[idx] = s * 0.125f + bo[j];
    return;
  }
  const int j = bid - 16;
  if (j < 1024) {
    const int rb = j & 7, kt = (j >> 3) & 31, z = j >> 8;
    build_img(FTpart + (size_t)z * 1048576, 0, 2, 4194304, rb, kt, tile,
              FTimg + ((size_t)(z * 8 + rb) * 32 + kt) * 8192);
  } else {
    const int qid = j - 1024;  // small path: all 4 batches
    const int b = qid >> 9, rem = qid & 511, rb = rem & 15, kt = rem >> 4;
    build_img(query + (size_t)b * 2097152, 0, 1, 0, rb, kt, tile,
              Qimg + ((size_t)(b * 16 + rb) * 32 + kt) * 8192);
  }
}

extern "C" void kernel_launch(void* const* d_in, const int* in_sizes, int n_in,
                              void* d_out, int out_size, void* d_ws,
                              size_t ws_size, hipStream_t stream) {
  const float* query = (const float*)d_in[0];
  const float* key = (const float*)d_in[1];
  const float* value = (const float*)d_in[2];
  const float* Wq = (const float*)d_in[3];
  const float* bq = (const float*)d_in[4];
  const float* Wk = (const float*)d_in[5];
  const float* bk = (const float*)d_in[6];
  const float* Wv = (const float*)d_in[7];
  const float* bv = (const float*)d_in[8];
  const float* Wo = (const float*)d_in[9];
  const float* bo = (const float*)d_in[10];
  float* out = (float*)d_out;
  float* ws = (float*)d_ws;

  // big path peak = 100,892,672 B (same as rounds 7-9, proven available).
  const bool big = ws_size >= (size_t)100892672;
  const int dsplit = big ? 2 : 1;

  // ---- layout (float offsets). Timeline-audited.
  // [0,64MiB)  KT(z0-3)+VT(z4-7) imgs -> WqMimg[0,16) -> FTimg[0,16) (big)
  //            WkTimg[16,20); WoTimg[20,24); Mpart[24,28); Msum[28,29)
  // [32,64)    Tpart -> FTpart
  // [64,*)     kvpart (early) -> Dpart -> Qimg [64,96) (big)
  // small: Qimg [0,32) built in imgb2; FTimg [64,80).
  unsigned short* KTimg = (unsigned short*)ws;
  unsigned short* VTimg = (unsigned short*)ws + 16777216;     // 32MiB
  float* kvpart = ws + 16777216;                              // 64MiB (early)
  float* Dpart = ws + 16777216;                               // 64MiB
  unsigned short* Dimg = (unsigned short*)ws;                 // 0
  unsigned short* WkTimg = (unsigned short*)(ws + 4194304);   // 16MiB
  unsigned short* WoTimg = WkTimg + 2097152;                  // 20MiB
  float* Mpart = ws + 6291456;                                // 24MiB
  float* Msum = ws + 7340032;                                 // 28MiB
  float* Tpart = ws + 8388608;                                // 32MiB
  unsigned short* WqMimg = (unsigned short*)ws;               // 0 (Dimg dead)
  float* FTpart = ws + 8388608;                               // 32MiB
  unsigned short* Qimg = big ? (unsigned short*)(ws + 16777216)   // 64MiB
                             : (unsigned short*)ws;               // 0 (small)
  unsigned short* FTimg = big ? (unsigned short*)ws               // 0
                              : (unsigned short*)(ws + 16777216); // 64MiB
  float* smalls = ws + (big ? 25165824 : 20971520);
  float* uv = smalls;              // 8192
  float* bqM = smalls + 8192;      // 4096
  float* cvpartb = smalls + 12288; // 32768
  float* cv = smalls + 45056;      // 4096

  // ---- 1: key^T/value^T images + fused column-sum partials
  kvimg<<<dim3(8, 64, 8), 256, 0, stream>>>(key, value, KTimg, kvpart);
  // ---- 2: uv = {Wk^T ksum, Wv^T vsum} (kvpart consumed before D overwrites)
  uvdirect<<<32, 256, 0, stream>>>(kvpart, Wk, Wv, uv);

  // ---- 3: D[b] = value^T key (= C^T), K=2048
  gemm_img<<<dim3(8, 8, 4 * dsplit), 256, 0, stream>>>(
      VTimg, 4194304, KTimg, 4194304, (const float*)nullptr, 0, Dpart, 1048576,
      64, dsplit, 4194304);

  // ---- 4: Dimg + WkT + WoT images (KT region dead)
  imgA<<<dim3(8, 32, 6), 256, 0, stream>>>(Dpart, dsplit, Wk, Wo, Dimg,
                                           WkTimg, WoTimg);

  // ---- 5: T[b] = WkT . D^T, split-K x2 (VT dead)
  gemm_img<<<dim3(8, 8, 8), 256, 0, stream>>>(WkTimg, 0, Dimg, 2097152,
                                              (const float*)nullptr, 0, Tpart,
                                              1048576, 32, 2, 4194304);

  // ---- 6: mstep + (big) Q-image batches 0,1 on idle CUs (Dpart dead)
  mstepq<<<big ? 1280 : 256, 256, 0, stream>>>(Tpart, 4194304, Wv, Mpart,
                                               query, Qimg);
  // ---- 7: M = sum(Mpart) + rank-1 corrections
  reduce4corr<<<1024, 256, 0, stream>>>(Mpart, uv, bk, bv, Msum);

  // ---- 8: WqM image (Dimg dead) + bqM + (big) Q-image batches 2,3
  wqmq<<<big ? 1536 : 512, 256, 0, stream>>>(Msum, Wq, bq, WqMimg, bqM, query,
                                             Qimg);

  // ---- 9: cvpart + FT gemm (Tpart dead)
  ftcombo<<<544, 256, 0, stream>>>(bqM, Wo, cvpartb, WoTimg, WqMimg, FTpart);

  // ---- 10: cvred + FTimg (+ small-path Qimg; WqMimg dead)
  imgb2<<<big ? 1040 : 3088, 256, 0, stream>>>(cvpartb, bo, cv, FTpart, FTimg,
                                               query, Qimg);

  // ---- 11: out[b] = query[b] @ FT[b]^T + cv[b]
  gemm_img<<<dim3(16, 8, 4), 256, 0, stream>>>(Qimg, 4194304, FTimg, 2097152,
                                               cv, 1024, out, 2097152, 32, 1,
                                               0);
}

// Round 11
// 242.201 us; speedup vs baseline: 1.1198x; 1.1198x over previous
//
#include <hip/hip_runtime.h>

// ---------------------------------------------------------------------------
// MHA without softmax, fully reassociated:
//   out[b] = query[b] @ F[b] + cv[b]
//   F[b]   = 0.125 * WqM[b] @ Wo,  WqM[b] = Wq . blockdiag_h(M[b,h])
//   M[b,h] = Wk_h^T C[b] Wv_h + (Wk_h^T ksum) bv_h^T + bk_h (vsum^T Wv_h) + S bk_h bv_h^T
//   C[b]   = key[b]^T value[b]   (D := value^T key = C^T)
// Round 11: round-10 structure (Q-build overlapped into mstep/wqm launches,
// ftcombo, imgb2) MINUS the uvdirect regression (58.7us latency-bound, 32
// blocks, VGPR=20 -> ~2 loads in flight). Reverted to the proven round-9
// trio reduceks/uvpart/reduceuv (~10us total).
// ---------------------------------------------------------------------------

typedef __attribute__((ext_vector_type(8))) short short8;
typedef __attribute__((ext_vector_type(8))) unsigned short ushort8;
typedef __attribute__((ext_vector_type(4))) float f32x4;

__device__ __forceinline__ unsigned short f2bf(float x) {
  unsigned u = __builtin_bit_cast(unsigned, x);
  u += 0x7fffu + ((u >> 16) & 1u);  // RNE
  return (unsigned short)(u >> 16);
}
__device__ __forceinline__ float bf2f(unsigned short b) {
  unsigned u = ((unsigned)b) << 16;
  return __builtin_bit_cast(float, u);
}

__device__ __forceinline__ void gload16(const unsigned short* g, unsigned short* l) {
  __builtin_amdgcn_global_load_lds(
      (const __attribute__((address_space(1))) unsigned int*)g,
      (__attribute__((address_space(3))) unsigned int*)l, 16, 0, 0);
}

// ---------------------------------------------------------------------------
// build_img: stage one 128x32 tile of logical R[rows][K] into LDS (fp32),
// then write the split-bf16 blob: 8192 ushorts = hi[4][128][8] || lo[4][128][8]
// ---------------------------------------------------------------------------
__device__ __forceinline__ void build_img(const float* __restrict__ s,
                                          int transposed, int nsum,
                                          long long sumStride, int rb, int kt,
                                          float (*tile)[36],
                                          unsigned short* __restrict__ blob) {
  const int t = threadIdx.x;
  if (!transposed) {
#pragma unroll
    for (int p = 0; p < 4; ++p) {
      const int idx = p * 1024 + t * 4;
      const int r = idx >> 5, k = idx & 31;
      const size_t off = (size_t)(rb * 128 + r) * 1024 + kt * 32 + k;
      float4 v = *(const float4*)&s[off];
      if (nsum == 2) {
        float4 u = *(const float4*)&s[off + sumStride];
        v.x += u.x; v.y += u.y; v.z += u.z; v.w += u.w;
      }
      *(float4*)&tile[r][k] = v;
    }
  } else {
#pragma unroll
    for (int p = 0; p < 4; ++p) {
      const int idx = p * 1024 + t * 4;
      const int k = idx >> 7, r = idx & 127;
      const size_t off = (size_t)(kt * 32 + k) * 1024 + rb * 128 + r;
      float4 v = *(const float4*)&s[off];
      tile[r + 0][k] = v.x;
      tile[r + 1][k] = v.y;
      tile[r + 2][k] = v.z;
      tile[r + 3][k] = v.w;
    }
  }
  __syncthreads();
  const int r = t >> 1, kh = (t & 1) * 16;
  ushort8 hi0, lo0, hi1, lo1;
#pragma unroll
  for (int j = 0; j < 8; ++j) {
    float x = tile[r][kh + j];
    unsigned short h = f2bf(x);
    hi0[j] = h;
    lo0[j] = f2bf(x - bf2f(h));
    float y = tile[r][kh + 8 + j];
    unsigned short g = f2bf(y);
    hi1[j] = g;
    lo1[j] = f2bf(y - bf2f(g));
  }
  const int k0sl = kh >> 3;  // 0 or 2
  *(ushort8*)&blob[k0sl * 1024 + r * 8] = hi0;
  *(ushort8*)&blob[(k0sl + 1) * 1024 + r * 8] = hi1;
  *(ushort8*)&blob[4096 + k0sl * 1024 + r * 8] = lo0;
  *(ushort8*)&blob[4096 + (k0sl + 1) * 1024 + r * 8] = lo1;
}

// ---------------------------------------------------------------------------
// gemm_core: C[m][n] (+bias[n]) = sum_k A[m][k]*BT[n][k], split-bf16 3-MFMA.
// 128x128 tile, BK=32, 4 waves; LDS double-buffer via global_load_lds.
// ---------------------------------------------------------------------------
__device__ __forceinline__ void gemm_core(
    unsigned short (*sAB)[16384], int bx, int by, int bz0,
    const unsigned short* __restrict__ Aimg, long long sAb,
    const unsigned short* __restrict__ Bimg, long long sBb,
    const float* __restrict__ bias, long long sBiasB, float* __restrict__ C,
    long long sCb, int NKT, int nsplit, long long sSplit) {
  const int tid = threadIdx.x, w = tid >> 6, l = tid & 63;
  const int batch = bz0 / nsplit, split = bz0 - batch * nsplit;
  const int NKT0 = NKT / nsplit, kt0 = split * NKT0;

  const unsigned short* Ab = Aimg + (size_t)batch * sAb + (size_t)bx * NKT * 8192;
  const unsigned short* Bb = Bimg + (size_t)batch * sBb + (size_t)by * NKT * 8192;

  f32x4 acc[4][4];
#pragma unroll
  for (int m = 0; m < 4; ++m)
#pragma unroll
    for (int n = 0; n < 4; ++n) acc[m][n] = f32x4{0.f, 0.f, 0.f, 0.f};

  const int wr = (w >> 1) * 64, wc = (w & 1) * 64, lr = l & 15, ksl = l >> 4;
  const int stg = w * 512 + l * 8;

#define STAGE(KT, BUF)                                                        \
  {                                                                           \
    const unsigned short* As_ = Ab + (size_t)(KT)*8192;                       \
    const unsigned short* Bs_ = Bb + (size_t)(KT)*8192;                       \
    _Pragma("unroll") for (int i = 0; i < 4; ++i)                             \
        gload16(As_ + i * 2048 + stg, &sAB[BUF][i * 2048 + w * 512]);         \
    _Pragma("unroll") for (int i = 0; i < 4; ++i)                             \
        gload16(Bs_ + i * 2048 + stg, &sAB[BUF][8192 + i * 2048 + w * 512]);  \
  }

  STAGE(kt0, 0);
  for (int kk = 0; kk < NKT0; ++kk) {
    __syncthreads();  // drains vmcnt(0): buf kk&1 ready; prev reads done
    if (kk + 1 < NKT0) STAGE(kt0 + kk + 1, (kk + 1) & 1);
    const unsigned short* sb = sAB[kk & 1];
    short8 ah[4], al[4], bh[4], bl[4];
#pragma unroll
    for (int m = 0; m < 4; ++m) {
      const int ro = ksl * 1024 + (wr + m * 16 + lr) * 8;
      ah[m] = *(const short8*)&sb[ro];
      al[m] = *(const short8*)&sb[4096 + ro];
    }
#pragma unroll
    for (int n = 0; n < 4; ++n) {
      const int ro = ksl * 1024 + (wc + n * 16 + lr) * 8;
      bh[n] = *(const short8*)&sb[8192 + ro];
      bl[n] = *(const short8*)&sb[12288 + ro];
    }
#pragma unroll
    for (int m = 0; m < 4; ++m)
#pragma unroll
      for (int n = 0; n < 4; ++n) {
        acc[m][n] = __builtin_amdgcn_mfma_f32_16x16x32_bf16(ah[m], bh[n], acc[m][n], 0, 0, 0);
        acc[m][n] = __builtin_amdgcn_mfma_f32_16x16x32_bf16(ah[m], bl[n], acc[m][n], 0, 0, 0);
        acc[m][n] = __builtin_amdgcn_mfma_f32_16x16x32_bf16(al[m], bh[n], acc[m][n], 0, 0, 0);
      }
  }
#undef STAGE

  float* Cb = C + (size_t)split * sSplit + (size_t)batch * sCb;
  const size_t m0 = (size_t)bx * 128, n0 = (size_t)by * 128;
#pragma unroll
  for (int n = 0; n < 4; ++n) {
    const size_t col = n0 + wc + n * 16 + lr;
    const float bval = bias ? bias[(size_t)batch * sBiasB + col] : 0.0f;
#pragma unroll
    for (int m = 0; m < 4; ++m) {
      const size_t rb = m0 + wr + m * 16 + ksl * 4;
#pragma unroll
      for (int r = 0; r < 4; ++r)
        Cb[(rb + r) * 1024 + col] = acc[m][n][r] + bval;
    }
  }
}

// generic 3D-grid gemm (D, T, final)
__global__ __launch_bounds__(256) void gemm_img(
    const unsigned short* __restrict__ Aimg, long long sAb,
    const unsigned short* __restrict__ Bimg, long long sBb,
    const float* __restrict__ bias, long long sBiasB, float* __restrict__ C,
    long long sCb, int NKT, int nsplit, long long sSplit) {
  __shared__ __align__(16) unsigned short sAB[2][16384];
  const int gx = gridDim.x, gy = gridDim.y;
  int flat = blockIdx.x + gx * (blockIdx.y + gy * blockIdx.z);
  const int total = gx * gy * gridDim.z;
  flat = (flat & 7) * (total >> 3) + (flat >> 3);
  const int bx = flat % gx;
  const int rest = flat / gx;
  gemm_core(sAB, bx, rest % gy, rest / gy, Aimg, sAb, Bimg, sBb, bias, sBiasB,
            C, sCb, NKT, nsplit, sSplit);
}

// ---------------------------------------------------------------------------
// kvimg: images of key^T (z0-3) and value^T (z4-7) + fused column-sum
// partials. grid (8,64,8).
// ---------------------------------------------------------------------------
__global__ __launch_bounds__(256) void kvimg(const float* __restrict__ key,
                                             const float* __restrict__ value,
                                             unsigned short* __restrict__ KTimg,
                                             float* __restrict__ kvpart) {
  __shared__ __align__(16) float tile[128][36];
  const int rb = blockIdx.x, kt = blockIdx.y, z = blockIdx.z;
  const float* s = (z < 4) ? key + (size_t)z * 2097152
                           : value + (size_t)(z - 4) * 2097152;
  unsigned short* blob = KTimg + ((size_t)(z * 8 + rb) * 64 + kt) * 8192;
  build_img(s, 1, 1, 0, rb, kt, tile, blob);
  const int t = threadIdx.x, r = t >> 1, kh = (t & 1) * 16;
  float sum = 0.f;
#pragma unroll
  for (int j = 0; j < 16; ++j) sum += tile[r][kh + j];
  sum += __shfl_xor(sum, 1);
  if ((t & 1) == 0)
    kvpart[((size_t)z * 64 + kt) * 1024 + rb * 128 + r] = sum;
}

// ksum[b][d] = sum_kt kvpart[b][kt][d]; vsum from z=4+b
__global__ __launch_bounds__(256) void reduceks(const float* __restrict__ kvpart,
                                                float* __restrict__ ksum,
                                                float* __restrict__ vsum) {
  const int idx = blockIdx.x * 256 + threadIdx.x;  // 4096
  const int b = idx >> 10, d = idx & 1023;
  float sk = 0.f, sv = 0.f;
  for (int kt = 0; kt < 64; ++kt) {
    sk += kvpart[((size_t)b * 64 + kt) * 1024 + d];
    sv += kvpart[((size_t)(4 + b) * 64 + kt) * 1024 + d];
  }
  ksum[idx] = sk;
  vsum[idx] = sv;
}

// uvpartb[((kv*4+b)*8+dc)*1024+i] = sum_{d in dc-chunk(128)} W[d][i]*s[d]
__global__ __launch_bounds__(256) void uvpart_kernel(
    const float* __restrict__ Wk, const float* __restrict__ Wv,
    const float* __restrict__ ksum, const float* __restrict__ vsum,
    float* __restrict__ part) {
  const int iseg = blockIdx.x;                          // 4
  const int dc = blockIdx.y & 7, kv = blockIdx.y >> 3;  // y: 16
  const int b = blockIdx.z;
  const int i = iseg * 256 + threadIdx.x;
  const float* W = kv ? Wv : Wk;
  const float* sv = (kv ? vsum : ksum) + b * 1024 + dc * 128;
  float s = 0.f;
  for (int dd = 0; dd < 128; ++dd)
    s += W[(size_t)(dc * 128 + dd) * 1024 + i] * sv[dd];
  part[(((size_t)kv * 4 + b) * 8 + dc) * 1024 + i] = s;
}

__global__ __launch_bounds__(256) void reduceuv(const float* __restrict__ part,
                                                float* __restrict__ uv) {
  const int idx = blockIdx.x * 256 + threadIdx.x;  // 8192
  const int kb = idx >> 10, i = idx & 1023;
  float s = 0.f;
#pragma unroll
  for (int dc = 0; dc < 8; ++dc) s += part[((size_t)kb * 8 + dc) * 1024 + i];
  uv[idx] = s;
}

// ---------------------------------------------------------------------------
// imgA: Dimg (z0-3, nsum=dsplit) + WkT (z4) + WoT (z5). grid (8,32,6).
// ---------------------------------------------------------------------------
__global__ __launch_bounds__(256) void imgA(
    const float* __restrict__ Dpart, int dsplit, const float* __restrict__ Wk,
    const float* __restrict__ Wo, unsigned short* __restrict__ Dimg,
    unsigned short* __restrict__ WkTimg, unsigned short* __restrict__ WoTimg) {
  __shared__ __align__(16) float tile[128][36];
  const int rb = blockIdx.x, kt = blockIdx.y, z = blockIdx.z;
  if (z < 4) {
    unsigned short* blob = Dimg + ((size_t)(z * 8 + rb) * 32 + kt) * 8192;
    build_img(Dpart + (size_t)z * 1048576, 0, dsplit, 4194304, rb, kt, tile,
              blob);
  } else if (z == 4) {
    unsigned short* blob = WkTimg + ((size_t)rb * 32 + kt) * 8192;
    build_img(Wk, 1, 1, 0, rb, kt, tile, blob);
  } else {
    unsigned short* blob = WoTimg + ((size_t)rb * 32 + kt) * 8192;
    build_img(Wo, 1, 1, 0, rb, kt, tile, blob);
  }
}

// ---------------------------------------------------------------------------
// mstepq: mstep (bid<256) + Q-image batches 0,1 (bid 256..1279).
// ---------------------------------------------------------------------------
__global__ __launch_bounds__(256) void mstepq(const float* __restrict__ T,
                                              long long tSplit,
                                              const float* __restrict__ Wv,
                                              float* __restrict__ Mpart,
                                              const float* __restrict__ query,
                                              unsigned short* __restrict__ Qimg) {
  __shared__ __align__(16) float sh[2 * 64 * 68];
  const int bid = blockIdx.x;
  const int tid = threadIdx.x;
  if (bid >= 256) {
    const int qid = bid - 256;  // [0,1024): batches 0,1
    const int b = qid >> 9, rem = qid & 511, rb = rem & 15, kt = rem >> 4;
    build_img(query + (size_t)b * 2097152, 0, 1, 0, rb, kt,
              (float(*)[36])sh, Qimg + ((size_t)(b * 16 + rb) * 32 + kt) * 8192);
    return;
  }
  const int chunk = bid & 3, bh = bid >> 2;
  const int b = bh >> 4, h = bh & 15;
  float (*Ts)[68] = (float(*)[68])sh;
  float (*Ws)[68] = (float(*)[68])(sh + 64 * 68);
  const int r0 = tid >> 4, c0 = (tid & 15) * 4;
  float acc[4][4] = {};
  const int e0 = chunk * 256;
  for (int slab = 0; slab < 4; ++slab) {
    __syncthreads();
#pragma unroll
    for (int t = 0; t < 4; ++t) {
      const int task = tid + t * 256;
      const int si = task >> 4, c4 = (task & 15) * 4;
      const size_t toff = (size_t)b * 1048576 + (size_t)(h * 64 + si) * 1024 +
                          e0 + slab * 64 + c4;
      float4 tv = *(const float4*)&T[toff];
      float4 tu = *(const float4*)&T[toff + tSplit];
      tv.x += tu.x; tv.y += tu.y; tv.z += tu.z; tv.w += tu.w;
      *(float4*)&Ts[si][c4] = tv;
      *(float4*)&Ws[si][c4] =
          *(const float4*)&Wv[(size_t)(e0 + slab * 64 + si) * 1024 + h * 64 + c4];
    }
    __syncthreads();
    for (int e = 0; e < 64; ++e) {
      const float4 wv = *(const float4*)&Ws[e][c0];
#pragma unroll
      for (int i = 0; i < 4; ++i) {
        const float tt = Ts[r0 + 16 * i][e];
        acc[i][0] += tt * wv.x;
        acc[i][1] += tt * wv.y;
        acc[i][2] += tt * wv.z;
        acc[i][3] += tt * wv.w;
      }
    }
  }
  float* outp = Mpart + ((size_t)chunk * 64 + bh) * 4096;
#pragma unroll
  for (int i = 0; i < 4; ++i)
    *(float4*)&outp[(r0 + 16 * i) * 64 + c0] = *(float4*)&acc[i][0];
}

// M = sum(Mpart) + rank-1 bias corrections
__global__ __launch_bounds__(256) void reduce4corr(
    const float* __restrict__ Mpart, const float* __restrict__ uv,
    const float* __restrict__ bk, const float* __restrict__ bv,
    float* __restrict__ M) {
  const int idx = blockIdx.x * 256 + threadIdx.x;  // 262144
  const int bh = idx >> 12, b = bh >> 4, h = bh & 15;
  const int rc = idx & 4095;
  const int r = h * 64 + (rc >> 6), c = h * 64 + (rc & 63);
  float s = Mpart[idx] + Mpart[262144 + idx] + Mpart[524288 + idx] +
            Mpart[786432 + idx];
  s += uv[b * 1024 + r] * bv[c] + bk[r] * uv[4096 + b * 1024 + c] +
       2048.0f * bk[r] * bv[c];
  M[idx] = s;
}

// ---------------------------------------------------------------------------
// wqmq: wqm (bid<512, WqM split-bf16 image + bqM on dseg==0) + Q-image
// batches 2,3 (bid 512..1535).
// ---------------------------------------------------------------------------
__global__ __launch_bounds__(256) void wqmq(const float* __restrict__ M,
                                            const float* __restrict__ Wq,
                                            const float* __restrict__ bq,
                                            unsigned short* __restrict__ img,
                                            float* __restrict__ bqM,
                                            const float* __restrict__ query,
                                            unsigned short* __restrict__ Qimg) {
  __shared__ __align__(16) float sh[(128 + 64) * 68];
  const int bid = blockIdx.x;
  const int t = threadIdx.x;
  if (bid >= 512) {
    const int qid = 1024 + (bid - 512);  // batches 2,3
    const int b = qid >> 9, rem = qid & 511, rb = rem & 15, kt = rem >> 4;
    build_img(query + (size_t)b * 2097152, 0, 1, 0, rb, kt,
              (float(*)[36])sh, Qimg + ((size_t)(b * 16 + rb) * 32 + kt) * 8192);
    return;
  }
  const int dseg = bid & 7, h = (bid >> 3) & 15, b = bid >> 7;
  float (*WqS)[68] = (float(*)[68])sh;
  float (*Ms)[68] = (float(*)[68])(sh + 128 * 68);
#pragma unroll
  for (int it = 0; it < 8; ++it) {
    const int task = t + it * 256;
    const int row = task >> 4, c4 = (task & 15) * 4;
    *(float4*)&WqS[row][c4] =
        *(const float4*)&Wq[(size_t)(dseg * 128 + row) * 1024 + h * 64 + c4];
  }
#pragma unroll
  for (int it = 0; it < 4; ++it) {
    const int task = t + it * 256;
    const int row = task >> 4, c4 = (task & 15) * 4;
    *(float4*)&Ms[row][c4] =
        *(const float4*)&M[((size_t)(b * 16 + h)) * 4096 + row * 64 + c4];
  }
  __syncthreads();

  const int c0 = (t & 7) * 8;
  const int d0 = t >> 3;
  float4 a0[4], a1[4];
#pragma unroll
  for (int i = 0; i < 4; ++i) {
    a0[i] = float4{0.f, 0.f, 0.f, 0.f};
    a1[i] = float4{0.f, 0.f, 0.f, 0.f};
  }
  for (int r = 0; r < 64; ++r) {
    const float4 m0 = *(const float4*)&Ms[r][c0];
    const float4 m1 = *(const float4*)&Ms[r][c0 + 4];
#pragma unroll
    for (int i = 0; i < 4; ++i) {
      const float w = WqS[d0 + 32 * i][r];
      a0[i].x += w * m0.x; a0[i].y += w * m0.y; a0[i].z += w * m0.z; a0[i].w += w * m0.w;
      a1[i].x += w * m1.x; a1[i].y += w * m1.y; a1[i].z += w * m1.z; a1[i].w += w * m1.w;
    }
  }
  const int kt = h * 2 + (c0 >> 5);
  const int ksl = (c0 >> 3) & 3;
  unsigned short* blob = img + ((size_t)((b * 8 + dseg) * 32 + kt)) * 8192;
#pragma unroll
  for (int i = 0; i < 4; ++i) {
    const int r = d0 + 32 * i;
    float v[8] = {a0[i].x * 0.125f, a0[i].y * 0.125f, a0[i].z * 0.125f,
                  a0[i].w * 0.125f, a1[i].x * 0.125f, a1[i].y * 0.125f,
                  a1[i].z * 0.125f, a1[i].w * 0.125f};
    ushort8 hi, lo;
#pragma unroll
    for (int j = 0; j < 8; ++j) {
      unsigned short hh = f2bf(v[j]);
      hi[j] = hh;
      lo[j] = f2bf(v[j] - bf2f(hh));
    }
    *(ushort8*)&blob[ksl * 1024 + r * 8] = hi;
    *(ushort8*)&blob[4096 + ksl * 1024 + r * 8] = lo;
  }

  if (dseg == 0 && t < 64) {
    float s = 0.f;
#pragma unroll
    for (int r = 0; r < 64; ++r) s += bq[h * 64 + r] * Ms[r][t];
    bqM[(size_t)b * 1024 + h * 64 + t] = s;
  }
}

// ---------------------------------------------------------------------------
// ftcombo: cvpart (bid<32) + FT gemm (512 blocks, split-K x2).
// ---------------------------------------------------------------------------
__global__ __launch_bounds__(256) void ftcombo(
    const float* __restrict__ bqM, const float* __restrict__ Wo,
    float* __restrict__ cvpartb, const unsigned short* __restrict__ WoTimg,
    const unsigned short* __restrict__ WqMimg, float* __restrict__ FTpart) {
  __shared__ __align__(16) unsigned short sAB[2][16384];
  const int bid = blockIdx.x;
  if (bid < 32) {
    const int jseg = bid & 3, ks = bid >> 2;
    const int j = jseg * 256 + threadIdx.x;
    float s0 = 0.f, s1 = 0.f, s2 = 0.f, s3 = 0.f;
    for (int k = 0; k < 128; ++k) {
      const float wv = Wo[(size_t)(ks * 128 + k) * 1024 + j];
      s0 += bqM[ks * 128 + k] * wv;
      s1 += bqM[1024 + ks * 128 + k] * wv;
      s2 += bqM[2048 + ks * 128 + k] * wv;
      s3 += bqM[3072 + ks * 128 + k] * wv;
    }
    cvpartb[((size_t)0 * 8 + ks) * 1024 + j] = s0;
    cvpartb[((size_t)1 * 8 + ks) * 1024 + j] = s1;
    cvpartb[((size_t)2 * 8 + ks) * 1024 + j] = s2;
    cvpartb[((size_t)3 * 8 + ks) * 1024 + j] = s3;
    return;
  }
  const int flat0 = bid - 32;  // [0,512)
  const int flat = (flat0 & 7) * 64 + (flat0 >> 3);
  gemm_core(sAB, flat & 7, (flat >> 3) & 7, flat >> 6, WoTimg, 0, WqMimg,
            2097152, (const float*)nullptr, 0, FTpart, 1048576, 32, 2, 4194304);
}

// ---------------------------------------------------------------------------
// imgb2: cvred (bid<16) + FTimg build (1024) [+ Qimg build, small path only].
// ---------------------------------------------------------------------------
__global__ __launch_bounds__(256) void imgb2(
    const float* __restrict__ cvpartb, const float* __restrict__ bo,
    float* __restrict__ cv, const float* __restrict__ FTpart,
    unsigned short* __restrict__ FTimg, const float* __restrict__ query,
    unsigned short* __restrict__ Qimg) {
  __shared__ __align__(16) float tile[128][36];
  const int bid = blockIdx.x;
  if (bid < 16) {
    const int idx = bid * 256 + threadIdx.x;
    const int b = idx >> 10, j = idx & 1023;
    float s = 0.f;
#pragma unroll
    for (int ks = 0; ks < 8; ++ks)
      s += cvpartb[((size_t)b * 8 + ks) * 1024 + j];
    cv[idx] = s * 0.125f + bo[j];
    return;
  }
  const int j = bid - 16;
  if (j < 1024) {
    const int rb = j & 7, kt = (j >> 3) & 31, z = j >> 8;
    build_img(FTpart + (size_t)z * 1048576, 0, 2, 4194304, rb, kt, tile,
              FTimg + ((size_t)(z * 8 + rb) * 32 + kt) * 8192);
  } else {
    const int qid = j - 1024;  // small path: all 4 batches
    const int b = qid >> 9, rem = qid & 511, rb = rem & 15, kt = rem >> 4;
    build_img(query + (size_t)b * 2097152, 0, 1, 0, rb, kt, tile,
              Qimg + ((size_t)(b * 16 + rb) * 32 + kt) * 8192);
  }
}

extern "C" void kernel_launch(void* const* d_in, const int* in_sizes, int n_in,
                              void* d_out, int out_size, void* d_ws,
                              size_t ws_size, hipStream_t stream) {
  const float* query = (const float*)d_in[0];
  const float* key = (const float*)d_in[1];
  const float* value = (const float*)d_in[2];
  const float* Wq = (const float*)d_in[3];
  const float* bq = (const float*)d_in[4];
  const float* Wk = (const float*)d_in[5];
  const float* bk = (const float*)d_in[6];
  const float* Wv = (const float*)d_in[7];
  const float* bv = (const float*)d_in[8];
  const float* Wo = (const float*)d_in[9];
  const float* bo = (const float*)d_in[10];
  float* out = (float*)d_out;
  float* ws = (float*)d_ws;

  // big path peak = 100,892,672 B (proven available by rounds 7-10).
  const bool big = ws_size >= (size_t)100892672;
  const int dsplit = big ? 2 : 1;

  // ---- layout (float offsets). Timeline-audited.
  // [0,64MiB)  KT(z0-3)+VT(z4-7) imgs -> WqMimg[0,16) -> FTimg[0,16) (big)
  //            WkTimg[16,20); WoTimg[20,24); Mpart[24,28); Msum[28,29)
  // [32,64)    Tpart -> FTpart
  // [64,*)     kvpart+uvpartb (early) -> Dpart -> Qimg [64,96) (big)
  // small: Qimg [0,32) built in imgb2; FTimg [64,80).
  unsigned short* KTimg = (unsigned short*)ws;
  unsigned short* VTimg = (unsigned short*)ws + 16777216;     // 32MiB
  float* kvpart = ws + 16777216;                              // 64MiB (early)
  float* uvpartb = ws + 17301504;                             // 66MiB (early)
  float* Dpart = ws + 16777216;                               // 64MiB
  unsigned short* Dimg = (unsigned short*)ws;                 // 0
  unsigned short* WkTimg = (unsigned short*)(ws + 4194304);   // 16MiB
  unsigned short* WoTimg = WkTimg + 2097152;                  // 20MiB
  float* Mpart = ws + 6291456;                                // 24MiB
  float* Msum = ws + 7340032;                                 // 28MiB
  float* Tpart = ws + 8388608;                                // 32MiB
  unsigned short* WqMimg = (unsigned short*)ws;               // 0 (Dimg dead)
  float* FTpart = ws + 8388608;                               // 32MiB
  unsigned short* Qimg = big ? (unsigned short*)(ws + 16777216)   // 64MiB
                             : (unsigned short*)ws;               // 0 (small)
  unsigned short* FTimg = big ? (unsigned short*)ws               // 0
                              : (unsigned short*)(ws + 16777216); // 64MiB
  float* smalls = ws + (big ? 25165824 : 20971520);
  float* uv = smalls;              // 8192
  float* bqM = smalls + 8192;      // 4096
  float* cvpartb = smalls + 12288; // 32768
  float* cv = smalls + 45056;      // 4096
  float* ksum = smalls + 49152;    // 4096
  float* vsum = smalls + 53248;    // 4096

  // ---- 1: key^T/value^T images + fused column-sum partials
  kvimg<<<dim3(8, 64, 8), 256, 0, stream>>>(key, value, KTimg, kvpart);
  // ---- 2-4: uv = {Wk^T ksum, Wv^T vsum} (proven trio; consumed before D)
  reduceks<<<16, 256, 0, stream>>>(kvpart, ksum, vsum);
  uvpart_kernel<<<dim3(4, 16, 4), 256, 0, stream>>>(Wk, Wv, ksum, vsum,
                                                    uvpartb);
  reduceuv<<<32, 256, 0, stream>>>(uvpartb, uv);

  // ---- 5: D[b] = value^T key (= C^T), K=2048
  gemm_img<<<dim3(8, 8, 4 * dsplit), 256, 0, stream>>>(
      VTimg, 4194304, KTimg, 4194304, (const float*)nullptr, 0, Dpart, 1048576,
      64, dsplit, 4194304);

  // ---- 6: Dimg + WkT + WoT images (KT region dead)
  imgA<<<dim3(8, 32, 6), 256, 0, stream>>>(Dpart, dsplit, Wk, Wo, Dimg,
                                           WkTimg, WoTimg);

  // ---- 7: T[b] = WkT . D^T, split-K x2 (VT dead)
  gemm_img<<<dim3(8, 8, 8), 256, 0, stream>>>(WkTimg, 0, Dimg, 2097152,
                                              (const float*)nullptr, 0, Tpart,
                                              1048576, 32, 2, 4194304);

  // ---- 8: mstep + (big) Q-image batches 0,1 on idle CUs (Dpart dead)
  mstepq<<<big ? 1280 : 256, 256, 0, stream>>>(Tpart, 4194304, Wv, Mpart,
                                               query, Qimg);
  // ---- 9: M = sum(Mpart) + rank-1 corrections
  reduce4corr<<<1024, 256, 0, stream>>>(Mpart, uv, bk, bv, Msum);

  // ---- 10: WqM image (Dimg dead) + bqM + (big) Q-image batches 2,3
  wqmq<<<big ? 1536 : 512, 256, 0, stream>>>(Msum, Wq, bq, WqMimg, bqM, query,
                                             Qimg);

  // ---- 11: cvpart + FT gemm (Tpart dead)
  ftcombo<<<544, 256, 0, stream>>>(bqM, Wo, cvpartb, WoTimg, WqMimg, FTpart);

  // ---- 12: cvred + FTimg (+ small-path Qimg; WqMimg dead)
  imgb2<<<big ? 1040 : 3088, 256, 0, stream>>>(cvpartb, bo, cv, FTpart, FTimg,
                                               query, Qimg);

  // ---- 13: out[b] = query[b] @ FT[b]^T + cv[b]
  gemm_img<<<dim3(16, 8, 4), 256, 0, stream>>>(Qimg, 4194304, FTimg, 2097152,
                                               cv, 1024, out, 2097152, 32, 1,
                                               0);
}

// Round 12
// 242.138 us; speedup vs baseline: 1.1201x; 1.0003x over previous
//
#include <hip/hip_runtime.h>

// ---------------------------------------------------------------------------
// MHA without softmax, fully reassociated:
//   out[b] = query[b] @ F[b] + cv[b]
//   F[b]   = 0.125 * WqM[b] @ Wo,  WqM[b] = Wq . blockdiag_h(M[b,h])
//   M[b,h] = Wk_h^T C[b] Wv_h + (Wk_h^T ksum) bv_h^T + bk_h (vsum^T Wv_h) + S bk_h bv_h^T
//   C[b]   = key[b]^T value[b]   (D := value^T key = C^T)
// Round 12: fold pass (GEMM core untouched, 937 TF-eq ceiling):
//  - reduce4corr folded into wqmq's M staging (same fp32 order).
//  - reduceks+uvpart -> uvpart2 (128 blk); reduceuv rides in the D gemm
//    launch (ftcombo rider pattern; uvpartb aliased to cvpartb slot in
//    smalls -> no Dpart race).
//  13 -> 10 launches.
// ---------------------------------------------------------------------------

typedef __attribute__((ext_vector_type(8))) short short8;
typedef __attribute__((ext_vector_type(8))) unsigned short ushort8;
typedef __attribute__((ext_vector_type(4))) float f32x4;

__device__ __forceinline__ unsigned short f2bf(float x) {
  unsigned u = __builtin_bit_cast(unsigned, x);
  u += 0x7fffu + ((u >> 16) & 1u);  // RNE
  return (unsigned short)(u >> 16);
}
__device__ __forceinline__ float bf2f(unsigned short b) {
  unsigned u = ((unsigned)b) << 16;
  return __builtin_bit_cast(float, u);
}

__device__ __forceinline__ void gload16(const unsigned short* g, unsigned short* l) {
  __builtin_amdgcn_global_load_lds(
      (const __attribute__((address_space(1))) unsigned int*)g,
      (__attribute__((address_space(3))) unsigned int*)l, 16, 0, 0);
}

// ---------------------------------------------------------------------------
// build_img: stage one 128x32 tile of logical R[rows][K] into LDS (fp32),
// then write the split-bf16 blob: 8192 ushorts = hi[4][128][8] || lo[4][128][8]
// ---------------------------------------------------------------------------
__device__ __forceinline__ void build_img(const float* __restrict__ s,
                                          int transposed, int nsum,
                                          long long sumStride, int rb, int kt,
                                          float (*tile)[36],
                                          unsigned short* __restrict__ blob) {
  const int t = threadIdx.x;
  if (!transposed) {
#pragma unroll
    for (int p = 0; p < 4; ++p) {
      const int idx = p * 1024 + t * 4;
      const int r = idx >> 5, k = idx & 31;
      const size_t off = (size_t)(rb * 128 + r) * 1024 + kt * 32 + k;
      float4 v = *(const float4*)&s[off];
      if (nsum == 2) {
        float4 u = *(const float4*)&s[off + sumStride];
        v.x += u.x; v.y += u.y; v.z += u.z; v.w += u.w;
      }
      *(float4*)&tile[r][k] = v;
    }
  } else {
#pragma unroll
    for (int p = 0; p < 4; ++p) {
      const int idx = p * 1024 + t * 4;
      const int k = idx >> 7, r = idx & 127;
      const size_t off = (size_t)(kt * 32 + k) * 1024 + rb * 128 + r;
      float4 v = *(const float4*)&s[off];
      tile[r + 0][k] = v.x;
      tile[r + 1][k] = v.y;
      tile[r + 2][k] = v.z;
      tile[r + 3][k] = v.w;
    }
  }
  __syncthreads();
  const int r = t >> 1, kh = (t & 1) * 16;
  ushort8 hi0, lo0, hi1, lo1;
#pragma unroll
  for (int j = 0; j < 8; ++j) {
    float x = tile[r][kh + j];
    unsigned short h = f2bf(x);
    hi0[j] = h;
    lo0[j] = f2bf(x - bf2f(h));
    float y = tile[r][kh + 8 + j];
    unsigned short g = f2bf(y);
    hi1[j] = g;
    lo1[j] = f2bf(y - bf2f(g));
  }
  const int k0sl = kh >> 3;  // 0 or 2
  *(ushort8*)&blob[k0sl * 1024 + r * 8] = hi0;
  *(ushort8*)&blob[(k0sl + 1) * 1024 + r * 8] = hi1;
  *(ushort8*)&blob[4096 + k0sl * 1024 + r * 8] = lo0;
  *(ushort8*)&blob[4096 + (k0sl + 1) * 1024 + r * 8] = lo1;
}

// ---------------------------------------------------------------------------
// gemm_core: C[m][n] (+bias[n]) = sum_k A[m][k]*BT[n][k], split-bf16 3-MFMA.
// 128x128 tile, BK=32, 4 waves; LDS double-buffer via global_load_lds.
// ---------------------------------------------------------------------------
__device__ __forceinline__ void gemm_core(
    unsigned short (*sAB)[16384], int bx, int by, int bz0,
    const unsigned short* __restrict__ Aimg, long long sAb,
    const unsigned short* __restrict__ Bimg, long long sBb,
    const float* __restrict__ bias, long long sBiasB, float* __restrict__ C,
    long long sCb, int NKT, int nsplit, long long sSplit) {
  const int tid = threadIdx.x, w = tid >> 6, l = tid & 63;
  const int batch = bz0 / nsplit, split = bz0 - batch * nsplit;
  const int NKT0 = NKT / nsplit, kt0 = split * NKT0;

  const unsigned short* Ab = Aimg + (size_t)batch * sAb + (size_t)bx * NKT * 8192;
  const unsigned short* Bb = Bimg + (size_t)batch * sBb + (size_t)by * NKT * 8192;

  f32x4 acc[4][4];
#pragma unroll
  for (int m = 0; m < 4; ++m)
#pragma unroll
    for (int n = 0; n < 4; ++n) acc[m][n] = f32x4{0.f, 0.f, 0.f, 0.f};

  const int wr = (w >> 1) * 64, wc = (w & 1) * 64, lr = l & 15, ksl = l >> 4;
  const int stg = w * 512 + l * 8;

#define STAGE(KT, BUF)                                                        \
  {                                                                           \
    const unsigned short* As_ = Ab + (size_t)(KT)*8192;                       \
    const unsigned short* Bs_ = Bb + (size_t)(KT)*8192;                       \
    _Pragma("unroll") for (int i = 0; i < 4; ++i)                             \
        gload16(As_ + i * 2048 + stg, &sAB[BUF][i * 2048 + w * 512]);         \
    _Pragma("unroll") for (int i = 0; i < 4; ++i)                             \
        gload16(Bs_ + i * 2048 + stg, &sAB[BUF][8192 + i * 2048 + w * 512]);  \
  }

  STAGE(kt0, 0);
  for (int kk = 0; kk < NKT0; ++kk) {
    __syncthreads();  // drains vmcnt(0): buf kk&1 ready; prev reads done
    if (kk + 1 < NKT0) STAGE(kt0 + kk + 1, (kk + 1) & 1);
    const unsigned short* sb = sAB[kk & 1];
    short8 ah[4], al[4], bh[4], bl[4];
#pragma unroll
    for (int m = 0; m < 4; ++m) {
      const int ro = ksl * 1024 + (wr + m * 16 + lr) * 8;
      ah[m] = *(const short8*)&sb[ro];
      al[m] = *(const short8*)&sb[4096 + ro];
    }
#pragma unroll
    for (int n = 0; n < 4; ++n) {
      const int ro = ksl * 1024 + (wc + n * 16 + lr) * 8;
      bh[n] = *(const short8*)&sb[8192 + ro];
      bl[n] = *(const short8*)&sb[12288 + ro];
    }
#pragma unroll
    for (int m = 0; m < 4; ++m)
#pragma unroll
      for (int n = 0; n < 4; ++n) {
        acc[m][n] = __builtin_amdgcn_mfma_f32_16x16x32_bf16(ah[m], bh[n], acc[m][n], 0, 0, 0);
        acc[m][n] = __builtin_amdgcn_mfma_f32_16x16x32_bf16(ah[m], bl[n], acc[m][n], 0, 0, 0);
        acc[m][n] = __builtin_amdgcn_mfma_f32_16x16x32_bf16(al[m], bh[n], acc[m][n], 0, 0, 0);
      }
  }
#undef STAGE

  float* Cb = C + (size_t)split * sSplit + (size_t)batch * sCb;
  const size_t m0 = (size_t)bx * 128, n0 = (size_t)by * 128;
#pragma unroll
  for (int n = 0; n < 4; ++n) {
    const size_t col = n0 + wc + n * 16 + lr;
    const float bval = bias ? bias[(size_t)batch * sBiasB + col] : 0.0f;
#pragma unroll
    for (int m = 0; m < 4; ++m) {
      const size_t rb = m0 + wr + m * 16 + ksl * 4;
#pragma unroll
      for (int r = 0; r < 4; ++r)
        Cb[(rb + r) * 1024 + col] = acc[m][n][r] + bval;
    }
  }
}

// generic 3D-grid gemm (T, final)
__global__ __launch_bounds__(256) void gemm_img(
    const unsigned short* __restrict__ Aimg, long long sAb,
    const unsigned short* __restrict__ Bimg, long long sBb,
    const float* __restrict__ bias, long long sBiasB, float* __restrict__ C,
    long long sCb, int NKT, int nsplit, long long sSplit) {
  __shared__ __align__(16) unsigned short sAB[2][16384];
  const int gx = gridDim.x, gy = gridDim.y;
  int flat = blockIdx.x + gx * (blockIdx.y + gy * blockIdx.z);
  const int total = gx * gy * gridDim.z;
  flat = (flat & 7) * (total >> 3) + (flat >> 3);
  const int bx = flat % gx;
  const int rest = flat / gx;
  gemm_core(sAB, bx, rest % gy, rest / gy, Aimg, sAb, Bimg, sBb, bias, sBiasB,
            C, sCb, NKT, nsplit, sSplit);
}

// ---------------------------------------------------------------------------
// dgemm_uv: reduceuv rider (bid<32) + D gemm (256*dsplit blocks).
// Rider: uv[z*1024+i] = sum_dcq uvpartb[(z*4+dcq)*1024+i].
// ---------------------------------------------------------------------------
__global__ __launch_bounds__(256) void dgemm_uv(
    const float* __restrict__ uvpartb, float* __restrict__ uv,
    const unsigned short* __restrict__ VTimg,
    const unsigned short* __restrict__ KTimg, float* __restrict__ Dpart,
    int dsplit) {
  __shared__ __align__(16) unsigned short sAB[2][16384];
  const int bid = blockIdx.x;
  if (bid < 32) {
    const int idx = bid * 256 + threadIdx.x;  // 8192
    const int z = idx >> 10, i = idx & 1023;
    float s = 0.f;
#pragma unroll
    for (int dcq = 0; dcq < 4; ++dcq)
      s += uvpartb[((size_t)z * 4 + dcq) * 1024 + i];
    uv[idx] = s;
    return;
  }
  const int flat0 = bid - 32;  // [0, 256*dsplit)
  const int total = gridDim.x - 32;
  const int flat = (flat0 & 7) * (total >> 3) + (flat0 >> 3);
  gemm_core(sAB, flat & 7, (flat >> 3) & 7, flat >> 6, VTimg, 4194304, KTimg,
            4194304, (const float*)nullptr, 0, Dpart, 1048576, 64, dsplit,
            4194304);
}

// ---------------------------------------------------------------------------
// kvimg: images of key^T (z0-3) and value^T (z4-7) + fused column-sum
// partials. grid (8,64,8).
// ---------------------------------------------------------------------------
__global__ __launch_bounds__(256) void kvimg(const float* __restrict__ key,
                                             const float* __restrict__ value,
                                             unsigned short* __restrict__ KTimg,
                                             float* __restrict__ kvpart) {
  __shared__ __align__(16) float tile[128][36];
  const int rb = blockIdx.x, kt = blockIdx.y, z = blockIdx.z;
  const float* s = (z < 4) ? key + (size_t)z * 2097152
                           : value + (size_t)(z - 4) * 2097152;
  unsigned short* blob = KTimg + ((size_t)(z * 8 + rb) * 64 + kt) * 8192;
  build_img(s, 1, 1, 0, rb, kt, tile, blob);
  const int t = threadIdx.x, r = t >> 1, kh = (t & 1) * 16;
  float sum = 0.f;
#pragma unroll
  for (int j = 0; j < 16; ++j) sum += tile[r][kh + j];
  sum += __shfl_xor(sum, 1);
  if ((t & 1) == 0)
    kvpart[((size_t)z * 64 + kt) * 1024 + rb * 128 + r] = sum;
}

// ---------------------------------------------------------------------------
// uvpart2: merged reduceks+uvpart. grid 128 = (iseg 4)(dcq 4)(kv 2)(b 4).
// s[d] = sum_kt kvpart[z][kt][d] for d in dcq-chunk(256) (LDS),
// uvpartb[(z*4+dcq)*1024+i] = sum_d W[d][i]*s[d].
// ---------------------------------------------------------------------------
__global__ __launch_bounds__(256) void uvpart2(const float* __restrict__ kvpart,
                                               const float* __restrict__ Wk,
                                               const float* __restrict__ Wv,
                                               float* __restrict__ uvpartb) {
  __shared__ float s[256];
  const int bid = blockIdx.x;
  const int iseg = bid & 3, dcq = (bid >> 2) & 3, kv = (bid >> 4) & 1,
            b = bid >> 5;
  const int t = threadIdx.x;
  const int z = kv * 4 + b;
  {
    const int d = dcq * 256 + t;
    float a = 0.f;
    for (int kt = 0; kt < 64; ++kt)
      a += kvpart[((size_t)(z * 64 + kt)) * 1024 + d];
    s[t] = a;
  }
  __syncthreads();
  const float* W = kv ? Wv : Wk;
  const int i = iseg * 256 + t;
  float a = 0.f;
  for (int d = 0; d < 256; ++d)
    a += W[(size_t)(dcq * 256 + d) * 1024 + i] * s[d];
  uvpartb[((size_t)z * 4 + dcq) * 1024 + i] = a;
}

// ---------------------------------------------------------------------------
// imgA: Dimg (z0-3, nsum=dsplit) + WkT (z4) + WoT (z5). grid (8,32,6).
// ---------------------------------------------------------------------------
__global__ __launch_bounds__(256) void imgA(
    const float* __restrict__ Dpart, int dsplit, const float* __restrict__ Wk,
    const float* __restrict__ Wo, unsigned short* __restrict__ Dimg,
    unsigned short* __restrict__ WkTimg, unsigned short* __restrict__ WoTimg) {
  __shared__ __align__(16) float tile[128][36];
  const int rb = blockIdx.x, kt = blockIdx.y, z = blockIdx.z;
  if (z < 4) {
    unsigned short* blob = Dimg + ((size_t)(z * 8 + rb) * 32 + kt) * 8192;
    build_img(Dpart + (size_t)z * 1048576, 0, dsplit, 4194304, rb, kt, tile,
              blob);
  } else if (z == 4) {
    unsigned short* blob = WkTimg + ((size_t)rb * 32 + kt) * 8192;
    build_img(Wk, 1, 1, 0, rb, kt, tile, blob);
  } else {
    unsigned short* blob = WoTimg + ((size_t)rb * 32 + kt) * 8192;
    build_img(Wo, 1, 1, 0, rb, kt, tile, blob);
  }
}

// ---------------------------------------------------------------------------
// mstepq: mstep (bid<256) + Q-image batches 0,1 (bid 256..1279).
// ---------------------------------------------------------------------------
__global__ __launch_bounds__(256) void mstepq(const float* __restrict__ T,
                                              long long tSplit,
                                              const float* __restrict__ Wv,
                                              float* __restrict__ Mpart,
                                              const float* __restrict__ query,
                                              unsigned short* __restrict__ Qimg) {
  __shared__ __align__(16) float sh[2 * 64 * 68];
  const int bid = blockIdx.x;
  const int tid = threadIdx.x;
  if (bid >= 256) {
    const int qid = bid - 256;  // [0,1024): batches 0,1
    const int b = qid >> 9, rem = qid & 511, rb = rem & 15, kt = rem >> 4;
    build_img(query + (size_t)b * 2097152, 0, 1, 0, rb, kt,
              (float(*)[36])sh, Qimg + ((size_t)(b * 16 + rb) * 32 + kt) * 8192);
    return;
  }
  const int chunk = bid & 3, bh = bid >> 2;
  const int b = bh >> 4, h = bh & 15;
  float (*Ts)[68] = (float(*)[68])sh;
  float (*Ws)[68] = (float(*)[68])(sh + 64 * 68);
  const int r0 = tid >> 4, c0 = (tid & 15) * 4;
  float acc[4][4] = {};
  const int e0 = chunk * 256;
  for (int slab = 0; slab < 4; ++slab) {
    __syncthreads();
#pragma unroll
    for (int t = 0; t < 4; ++t) {
      const int task = tid + t * 256;
      const int si = task >> 4, c4 = (task & 15) * 4;
      const size_t toff = (size_t)b * 1048576 + (size_t)(h * 64 + si) * 1024 +
                          e0 + slab * 64 + c4;
      float4 tv = *(const float4*)&T[toff];
      float4 tu = *(const float4*)&T[toff + tSplit];
      tv.x += tu.x; tv.y += tu.y; tv.z += tu.z; tv.w += tu.w;
      *(float4*)&Ts[si][c4] = tv;
      *(float4*)&Ws[si][c4] =
          *(const float4*)&Wv[(size_t)(e0 + slab * 64 + si) * 1024 + h * 64 + c4];
    }
    __syncthreads();
    for (int e = 0; e < 64; ++e) {
      const float4 wv = *(const float4*)&Ws[e][c0];
#pragma unroll
      for (int i = 0; i < 4; ++i) {
        const float tt = Ts[r0 + 16 * i][e];
        acc[i][0] += tt * wv.x;
        acc[i][1] += tt * wv.y;
        acc[i][2] += tt * wv.z;
        acc[i][3] += tt * wv.w;
      }
    }
  }
  float* outp = Mpart + ((size_t)chunk * 64 + bh) * 4096;
#pragma unroll
  for (int i = 0; i < 4; ++i)
    *(float4*)&outp[(r0 + 16 * i) * 64 + c0] = *(float4*)&acc[i][0];
}

// ---------------------------------------------------------------------------
// wqmq: wqm with FUSED Mpart-reduce + rank-1 corrections (bid<512; writes
// WqM split-bf16 image + bqM on dseg==0) + Q-image batches 2,3 (bid>=512).
// ---------------------------------------------------------------------------
__global__ __launch_bounds__(256) void wqmq(
    const float* __restrict__ Mpart, const float* __restrict__ Wq,
    const float* __restrict__ bq, const float* __restrict__ uv,
    const float* __restrict__ bk, const float* __restrict__ bv,
    unsigned short* __restrict__ img, float* __restrict__ bqM,
    const float* __restrict__ query, unsigned short* __restrict__ Qimg) {
  __shared__ __align__(16) float sh[(128 + 64) * 68];
  const int bid = blockIdx.x;
  const int t = threadIdx.x;
  if (bid >= 512) {
    const int qid = 1024 + (bid - 512);  // batches 2,3
    const int b = qid >> 9, rem = qid & 511, rb = rem & 15, kt = rem >> 4;
    build_img(query + (size_t)b * 2097152, 0, 1, 0, rb, kt,
              (float(*)[36])sh, Qimg + ((size_t)(b * 16 + rb) * 32 + kt) * 8192);
    return;
  }
  const int dseg = bid & 7, h = (bid >> 3) & 15, b = bid >> 7;
  float (*WqS)[68] = (float(*)[68])sh;
  float (*Ms)[68] = (float(*)[68])(sh + 128 * 68);
#pragma unroll
  for (int it = 0; it < 8; ++it) {
    const int task = t + it * 256;
    const int row = task >> 4, c4 = (task & 15) * 4;
    *(float4*)&WqS[row][c4] =
        *(const float4*)&Wq[(size_t)(dseg * 128 + row) * 1024 + h * 64 + c4];
  }
  // Ms = sum of 4 Mpart chunks + rank-1 bias corrections (== old reduce4corr)
#pragma unroll
  for (int it = 0; it < 4; ++it) {
    const int task = t + it * 256;
    const int row = task >> 4, c4 = (task & 15) * 4;
    const size_t off = (size_t)(b * 16 + h) * 4096 + row * 64 + c4;
    float4 v0 = *(const float4*)&Mpart[off];
    float4 v1 = *(const float4*)&Mpart[262144 + off];
    float4 v2 = *(const float4*)&Mpart[524288 + off];
    float4 v3 = *(const float4*)&Mpart[786432 + off];
    const int r = h * 64 + row;
    const float ur = uv[b * 1024 + r], bkr = bk[r];
    const float4 bvv = *(const float4*)&bv[h * 64 + c4];
    const float4 uvc = *(const float4*)&uv[4096 + b * 1024 + h * 64 + c4];
    float4 v;
    v.x = v0.x + v1.x + v2.x + v3.x + ur * bvv.x + bkr * uvc.x + 2048.0f * bkr * bvv.x;
    v.y = v0.y + v1.y + v2.y + v3.y + ur * bvv.y + bkr * uvc.y + 2048.0f * bkr * bvv.y;
    v.z = v0.z + v1.z + v2.z + v3.z + ur * bvv.z + bkr * uvc.z + 2048.0f * bkr * bvv.z;
    v.w = v0.w + v1.w + v2.w + v3.w + ur * bvv.w + bkr * uvc.w + 2048.0f * bkr * bvv.w;
    *(float4*)&Ms[row][c4] = v;
  }
  __syncthreads();

  const int c0 = (t & 7) * 8;
  const int d0 = t >> 3;
  float4 a0[4], a1[4];
#pragma unroll
  for (int i = 0; i < 4; ++i) {
    a0[i] = float4{0.f, 0.f, 0.f, 0.f};
    a1[i] = float4{0.f, 0.f, 0.f, 0.f};
  }
  for (int r = 0; r < 64; ++r) {
    const float4 m0 = *(const float4*)&Ms[r][c0];
    const float4 m1 = *(const float4*)&Ms[r][c0 + 4];
#pragma unroll
    for (int i = 0; i < 4; ++i) {
      const float w = WqS[d0 + 32 * i][r];
      a0[i].x += w * m0.x; a0[i].y += w * m0.y; a0[i].z += w * m0.z; a0[i].w += w * m0.w;
      a1[i].x += w * m1.x; a1[i].y += w * m1.y; a1[i].z += w * m1.z; a1[i].w += w * m1.w;
    }
  }
  const int kt = h * 2 + (c0 >> 5);
  const int ksl = (c0 >> 3) & 3;
  unsigned short* blob = img + ((size_t)((b * 8 + dseg) * 32 + kt)) * 8192;
#pragma unroll
  for (int i = 0; i < 4; ++i) {
    const int r = d0 + 32 * i;
    float v[8] = {a0[i].x * 0.125f, a0[i].y * 0.125f, a0[i].z * 0.125f,
                  a0[i].w * 0.125f, a1[i].x * 0.125f, a1[i].y * 0.125f,
                  a1[i].z * 0.125f, a1[i].w * 0.125f};
    ushort8 hi, lo;
#pragma unroll
    for (int j = 0; j < 8; ++j) {
      unsigned short hh = f2bf(v[j]);
      hi[j] = hh;
      lo[j] = f2bf(v[j] - bf2f(hh));
    }
    *(ushort8*)&blob[ksl * 1024 + r * 8] = hi;
    *(ushort8*)&blob[4096 + ksl * 1024 + r * 8] = lo;
  }

  if (dseg == 0 && t < 64) {
    float s = 0.f;
#pragma unroll
    for (int r = 0; r < 64; ++r) s += bq[h * 64 + r] * Ms[r][t];
    bqM[(size_t)b * 1024 + h * 64 + t] = s;
  }
}

// ---------------------------------------------------------------------------
// ftcombo: cvpart (bid<32) + FT gemm (512 blocks, split-K x2).
// ---------------------------------------------------------------------------
__global__ __launch_bounds__(256) void ftcombo(
    const float* __restrict__ bqM, const float* __restrict__ Wo,
    float* __restrict__ cvpartb, const unsigned short* __restrict__ WoTimg,
    const unsigned short* __restrict__ WqMimg, float* __restrict__ FTpart) {
  __shared__ __align__(16) unsigned short sAB[2][16384];
  const int bid = blockIdx.x;
  if (bid < 32) {
    const int jseg = bid & 3, ks = bid >> 2;
    const int j = jseg * 256 + threadIdx.x;
    float s0 = 0.f, s1 = 0.f, s2 = 0.f, s3 = 0.f;
    for (int k = 0; k < 128; ++k) {
      const float wv = Wo[(size_t)(ks * 128 + k) * 1024 + j];
      s0 += bqM[ks * 128 + k] * wv;
      s1 += bqM[1024 + ks * 128 + k] * wv;
      s2 += bqM[2048 + ks * 128 + k] * wv;
      s3 += bqM[3072 + ks * 128 + k] * wv;
    }
    cvpartb[((size_t)0 * 8 + ks) * 1024 + j] = s0;
    cvpartb[((size_t)1 * 8 + ks) * 1024 + j] = s1;
    cvpartb[((size_t)2 * 8 + ks) * 1024 + j] = s2;
    cvpartb[((size_t)3 * 8 + ks) * 1024 + j] = s3;
    return;
  }
  const int flat0 = bid - 32;  // [0,512)
  const int flat = (flat0 & 7) * 64 + (flat0 >> 3);
  gemm_core(sAB, flat & 7, (flat >> 3) & 7, flat >> 6, WoTimg, 0, WqMimg,
            2097152, (const float*)nullptr, 0, FTpart, 1048576, 32, 2, 4194304);
}

// ---------------------------------------------------------------------------
// imgb2: cvred (bid<16) + FTimg build (1024) [+ Qimg build, small path only].
// ---------------------------------------------------------------------------
__global__ __launch_bounds__(256) void imgb2(
    const float* __restrict__ cvpartb, const float* __restrict__ bo,
    float* __restrict__ cv, const float* __restrict__ FTpart,
    unsigned short* __restrict__ FTimg, const float* __restrict__ query,
    unsigned short* __restrict__ Qimg) {
  __shared__ __align__(16) float tile[128][36];
  const int bid = blockIdx.x;
  if (bid < 16) {
    const int idx = bid * 256 + threadIdx.x;
    const int b = idx >> 10, j = idx & 1023;
    float s = 0.f;
#pragma unroll
    for (int ks = 0; ks < 8; ++ks)
      s += cvpartb[((size_t)b * 8 + ks) * 1024 + j];
    cv[idx] = s * 0.125f + bo[j];
    return;
  }
  const int j = bid - 16;
  if (j < 1024) {
    const int rb = j & 7, kt = (j >> 3) & 31, z = j >> 8;
    build_img(FTpart + (size_t)z * 1048576, 0, 2, 4194304, rb, kt, tile,
              FTimg + ((size_t)(z * 8 + rb) * 32 + kt) * 8192);
  } else {
    const int qid = j - 1024;  // small path: all 4 batches
    const int b = qid >> 9, rem = qid & 511, rb = rem & 15, kt = rem >> 4;
    build_img(query + (size_t)b * 2097152, 0, 1, 0, rb, kt, tile,
              Qimg + ((size_t)(b * 16 + rb) * 32 + kt) * 8192);
  }
}

extern "C" void kernel_launch(void* const* d_in, const int* in_sizes, int n_in,
                              void* d_out, int out_size, void* d_ws,
                              size_t ws_size, hipStream_t stream) {
  const float* query = (const float*)d_in[0];
  const float* key = (const float*)d_in[1];
  const float* value = (const float*)d_in[2];
  const float* Wq = (const float*)d_in[3];
  const float* bq = (const float*)d_in[4];
  const float* Wk = (const float*)d_in[5];
  const float* bk = (const float*)d_in[6];
  const float* Wv = (const float*)d_in[7];
  const float* bv = (const float*)d_in[8];
  const float* Wo = (const float*)d_in[9];
  const float* bo = (const float*)d_in[10];
  float* out = (float*)d_out;
  float* ws = (float*)d_ws;

  // big path peak <= 100,892,672 B (proven available by rounds 7-11).
  const bool big = ws_size >= (size_t)100892672;
  const int dsplit = big ? 2 : 1;

  // ---- layout (float offsets). Timeline-audited.
  // [0,64MiB)  KT(z0-3)+VT(z4-7) imgs -> Dimg[0,16) -> WqMimg[0,16)
  //            -> FTimg[0,16) (big); WkTimg[16,20); WoTimg[20,24);
  //            Mpart[24,28)
  // [32,64)    Tpart -> FTpart
  // [64,*)     kvpart (early) -> Dpart -> Qimg [64,96) (big)
  // smalls @96MiB (big) | @80MiB (small): uv, bqM, cvpartb(=uvpartb alias,
  //            time-disjoint: uvpartb dead after dgemm_uv rider; cvpartb
  //            written at ftcombo), cv.
  // small path: Qimg [0,32) built in imgb2; FTimg [64,80).
  unsigned short* KTimg = (unsigned short*)ws;
  unsigned short* VTimg = (unsigned short*)ws + 16777216;     // 32MiB
  float* kvpart = ws + 16777216;                              // 64MiB (early)
  float* Dpart = ws + 16777216;                               // 64MiB
  unsigned short* Dimg = (unsigned short*)ws;                 // 0
  unsigned short* WkTimg = (unsigned short*)(ws + 4194304);   // 16MiB
  unsigned short* WoTimg = WkTimg + 2097152;                  // 20MiB
  float* Mpart = ws + 6291456;                                // 24MiB
  float* Tpart = ws + 8388608;                                // 32MiB
  unsigned short* WqMimg = (unsigned short*)ws;               // 0 (Dimg dead)
  float* FTpart = ws + 8388608;                               // 32MiB
  unsigned short* Qimg = big ? (unsigned short*)(ws + 16777216)   // 64MiB
                             : (unsigned short*)ws;               // 0 (small)
  unsigned short* FTimg = big ? (unsigned short*)ws               // 0
                              : (unsigned short*)(ws + 16777216); // 64MiB
  float* smalls = ws + (big ? 25165824 : 20971520);
  float* uv = smalls;               // 8192
  float* bqM = smalls + 8192;       // 4096
  float* cvpartb = smalls + 12288;  // 32768 (also uvpartb, time-disjoint)
  float* uvpartb = cvpartb;
  float* cv = smalls + 45056;       // 4096

  // ---- 1: key^T/value^T images + fused column-sum partials
  kvimg<<<dim3(8, 64, 8), 256, 0, stream>>>(key, value, KTimg, kvpart);

  // ---- 2: uvpartb = per-256-d-chunk W^T . (kt-summed colsum)
  uvpart2<<<128, 256, 0, stream>>>(kvpart, Wk, Wv, uvpartb);

  // ---- 3: D[b] = value^T key (= C^T), K=2048 + reduceuv rider
  dgemm_uv<<<32 + 256 * dsplit, 256, 0, stream>>>(uvpartb, uv, VTimg, KTimg,
                                                  Dpart, dsplit);

  // ---- 4: Dimg + WkT + WoT images (KT region dead)
  imgA<<<dim3(8, 32, 6), 256, 0, stream>>>(Dpart, dsplit, Wk, Wo, Dimg,
                                           WkTimg, WoTimg);

  // ---- 5: T[b] = WkT . D^T, split-K x2 (VT dead)
  gemm_img<<<dim3(8, 8, 8), 256, 0, stream>>>(WkTimg, 0, Dimg, 2097152,
                                              (const float*)nullptr, 0, Tpart,
                                              1048576, 32, 2, 4194304);

  // ---- 6: mstep + (big) Q-image batches 0,1 on idle CUs (Dpart dead)
  mstepq<<<big ? 1280 : 256, 256, 0, stream>>>(Tpart, 4194304, Wv, Mpart,
                                               query, Qimg);

  // ---- 7: WqM image (Dimg dead) with fused Mpart-reduce + corrections
  //         + bqM + (big) Q-image batches 2,3
  wqmq<<<big ? 1536 : 512, 256, 0, stream>>>(Mpart, Wq, bq, uv, bk, bv,
                                             WqMimg, bqM, query, Qimg);

  // ---- 8: cvpart + FT gemm (Tpart dead)
  ftcombo<<<544, 256, 0, stream>>>(bqM, Wo, cvpartb, WoTimg, WqMimg, FTpart);

  // ---- 9: cvred + FTimg (+ small-path Qimg; WqMimg dead)
  imgb2<<<big ? 1040 : 3088, 256, 0, stream>>>(cvpartb, bo, cv, FTpart, FTimg,
                                               query, Qimg);

  // ---- 10: out[b] = query[b] @ FT[b]^T + cv[b]
  gemm_img<<<dim3(16, 8, 4), 256, 0, stream>>>(Qimg, 4194304, FTimg, 2097152,
                                               cv, 1024, out, 2097152, 32, 1,
                                               0);
}